// Round 8
// baseline (273.951 us; speedup 1.0000x reference)
//
#include <hip/hip_runtime.h>
#include <math.h>

typedef __attribute__((ext_vector_type(8))) short bf16x8;
typedef __attribute__((ext_vector_type(4))) short bf16x4;
typedef __attribute__((ext_vector_type(4))) float f32x4;

#define LOG2E 1.4426950408889634f

#if __has_builtin(__builtin_amdgcn_exp2f)
#define EXP2(x) __builtin_amdgcn_exp2f(x)
#else
#define EXP2(x) exp2f(x)
#endif

static __device__ __forceinline__ short f2bf(float f) {
  unsigned u = __builtin_bit_cast(unsigned, f);
  u = u + 0x7FFFu + ((u >> 16) & 1u);   // RNE
  return (short)(u >> 16);
}

// ---------------------------------------------------------------------------
// K1: fused sigma + QKV projection. UNCHANGED round-4 version (control).
// ---------------------------------------------------------------------------
__global__ __launch_bounds__(256) void proj_fused(
    const float* __restrict__ x,
    const float* __restrict__ wf, const float* __restrict__ bf_,
    const float* __restrict__ uf,
    const float* __restrict__ wg, const float* __restrict__ bg_,
    const float* __restrict__ ug,
    const float* __restrict__ wh, const float* __restrict__ bh_,
    const float* __restrict__ uh,
    short* __restrict__ fo, short* __restrict__ go, short* __restrict__ hto) {
  __shared__ __align__(16) short wt[96 * 256];  // 48 KB (hsh aliases later)
  __shared__ float red[256];
  __shared__ float svx[256];
  __shared__ float scl[3];
  int tid = threadIdx.x;
  int wave = tid >> 6, lane = tid & 63;
  int quad = lane >> 4, l16 = lane & 15;
  int row0 = blockIdx.x * 64;

  // ---- prefetch x A-fragments (one row per lane, 8 k-chunks) ----
  const float* xr = x + (size_t)(row0 + wave * 16 + l16) * 256 + quad * 8;
  bf16x8 afv[8];
#pragma unroll
  for (int k8 = 0; k8 < 8; k8++) {
    float4 a0 = *(const float4*)(xr + k8 * 32);
    float4 a1 = *(const float4*)(xr + k8 * 32 + 4);
    bf16x8 a;
    a[0] = f2bf(a0.x); a[1] = f2bf(a0.y); a[2] = f2bf(a0.z); a[3] = f2bf(a0.w);
    a[4] = f2bf(a1.x); a[5] = f2bf(a1.y); a[6] = f2bf(a1.z); a[7] = f2bf(a1.w);
    afv[k8] = a;
  }

  // ---- per-sel: sigma + Wt build from the SAME register copy of w ----
#pragma unroll 1
  for (int sel = 0; sel < 3; sel++) {
    const float* w = (sel == 0) ? wf : (sel == 1) ? wg : wh;
    const float* u = (sel == 0) ? uf : (sel == 1) ? ug : uh;

    float wr[32];
    {
      const float4* wrow = (const float4*)(w + tid * 32);
#pragma unroll
      for (int q4 = 0; q4 < 8; q4++) {
        float4 v = wrow[q4];
        wr[4 * q4 + 0] = v.x; wr[4 * q4 + 1] = v.y;
        wr[4 * q4 + 2] = v.z; wr[4 * q4 + 3] = v.w;
      }
    }
    // stage 1: t = u . w[tid][:]
    float t = 0.f;
#pragma unroll
    for (int j = 0; j < 32; j++) t += u[j] * wr[j];
    float v2 = t * t;
#pragma unroll
    for (int off = 32; off > 0; off >>= 1) v2 += __shfl_xor(v2, off);
    if (lane == 0) red[wave] = v2;
    __syncthreads();
    float nv = sqrtf(fmaxf(red[0] + red[1] + red[2] + red[3], 1e-12f));
    svx[tid] = t / nv;
    __syncthreads();
    // stage 2: y[c] = sum_i sv[i] * w[i][c]  (coalesced, L1/L2-hot)
    int c = tid & 31, part = tid >> 5;
    float p = 0.f;
#pragma unroll
    for (int k = 0; k < 32; k++) {
      int i = part * 32 + k;
      p += svx[i] * w[i * 32 + c];
    }
    red[tid] = p;
    __syncthreads();
    float q2 = 0.f;
    if (tid < 32) {
      float s_c = 0.f;
#pragma unroll
      for (int pp = 0; pp < 8; pp++) s_c += red[tid + 32 * pp];
      q2 = s_c * s_c;
    }
#pragma unroll
    for (int off = 32; off > 0; off >>= 1) q2 += __shfl_xor(q2, off);
    if (tid == 0) {
      float s2 = q2;
      float sig = s2 / sqrtf(fmaxf(s2, 1e-12f));
      float s = 1.0f / sig;
      if (sel == 1) s *= LOG2E;
      scl[sel] = s;
    }
    __syncthreads();
    // build Wt rows sel*32..+31 straight from registers (swizzle unchanged)
    float s = scl[sel];
#pragma unroll
    for (int cc = 0; cc < 32; cc++) {
      wt[(sel * 32 + cc) * 256 + (tid ^ ((cc & 15) << 3))] = f2bf(wr[cc] * s);
    }
    __syncthreads();  // red/svx reused next sel; last iter guards MFMA reads
  }

  // ---- MFMA main loop ----
  f32x4 acc[6];
#pragma unroll
  for (int t = 0; t < 6; t++) acc[t] = (f32x4){0.f, 0.f, 0.f, 0.f};
#pragma unroll
  for (int k8 = 0; k8 < 8; k8++) {
    int kc = k8 * 32;
#pragma unroll
    for (int t = 0; t < 6; t++) {
      int rw = t * 16 + l16;
      bf16x8 bfr =
          *(const bf16x8*)&wt[rw * 256 + ((kc + quad * 8) ^ (l16 << 3))];
      acc[t] =
          __builtin_amdgcn_mfma_f32_16x16x32_bf16(afv[k8], bfr, acc[t], 0, 0, 0);
    }
  }
  __syncthreads();  // all wt reads done before hsh aliases it

  // ---- epilogue: f/g stores, h transpose via LDS ----
  float* hsh = (float*)wt;  // [64][33]
  int b = row0 >> 12;
  int n0 = row0 & 4095;
  int rbase = row0 + wave * 16;
#pragma unroll
  for (int t = 0; t < 4; t++) {
    int c = t * 16 + l16;
    int se = c >> 5, cc = c & 31;
    float bb = se ? (bg_[cc] * LOG2E) : bf_[cc];
    short* dst = se ? go : fo;
#pragma unroll
    for (int r = 0; r < 4; r++) {
      int row = rbase + quad * 4 + r;
      dst[(size_t)row * 32 + cc] = f2bf(acc[t][r] + bb);
    }
  }
#pragma unroll
  for (int t = 4; t < 6; t++) {
    int cc = (t - 4) * 16 + l16;
    float bb = bh_[cc];
#pragma unroll
    for (int r = 0; r < 4; r++)
      hsh[(wave * 16 + quad * 4 + r) * 33 + cc] = acc[t][r] + bb;
  }
  __syncthreads();
  {
    int d = tid >> 3, ng = tid & 7;
    bf16x8 tmp;
#pragma unroll
    for (int i = 0; i < 8; i++) tmp[i] = f2bf(hsh[(ng * 8 + i) * 33 + d]);
    *(bf16x8*)(hto + (size_t)(b * 32 + d) * 4096 + n0 + ng * 8) = tmp;
  }
}

// ---------------------------------------------------------------------------
// K2: flash attention. Round-7 sw-pipeline REVERTED (falsified: +2 us).
// THIS ROUND: combine the two individually-proven mechanisms —
//   (1) round-3 high-TLP config: 2 q-groups/wave, 2048 blocks = 8 blocks/CU,
//       launch_bounds(256,8), slim psh (9 KB), VGPR 32+24acc <= 64/wave.
//       Proven to engage (occupancy 33->66%) but was poisoned by L2 thrash.
//   (2) round-6 XCD remap: pins each XCD to 8 (b,z) combos -> per-XCD read
//       working set ~3 MB < 4 MiB L2, INDEPENDENT of blocks/CU. Proven to
//       cut FETCH 18.5->10.8 MB.
// Round-3's thrash precondition (cross-XCD combo interleave) is gone, so
// the TLP gain should now survive. Falsifier: FETCH >> 25 MB -> revert.
// ---------------------------------------------------------------------------
__global__ __launch_bounds__(256, 8) void attn_kernel(
    const short* __restrict__ g_, const short* __restrict__ f_,
    const short* __restrict__ ht_, short* __restrict__ po,
    float* __restrict__ ls) {
  __shared__ __align__(16) short psh[4][16][72];  // one P tile per wave
  int lin = blockIdx.x + (blockIdx.y << 5) + (blockIdx.z << 8);
  int xcd = lin & 7;
  int s8 = lin >> 3;                  // sequence index within XCD (0..255)
  int combo = xcd * 8 + (s8 >> 5);    // (b,z) combo 0..63, 8 per XCD
  int qt = s8 & 31;                   // q-tile 0..31
  int z = combo >> 3;
  int b = combo & 7;
  int wave = threadIdx.x >> 6;
  int lane = threadIdx.x & 63;
  int quad = lane >> 4, l16 = lane & 15;
  int qbase = qt * 128 + wave * 32;
  int kc0 = z * 512;

  const short* fb = f_ + (size_t)b * 4096 * 32;
  const short* hb = ht_ + (size_t)b * 32 * 4096;

  bf16x8 ga[2];
#pragma unroll
  for (int grp = 0; grp < 2; grp++)
    ga[grp] = *(const bf16x8*)(g_ + (size_t)(b * 4096 + qbase + grp * 16 + l16) * 32 +
                               quad * 8);

  f32x4 oacc[2][2];
  f32x4 lacc[2];
#pragma unroll
  for (int grp = 0; grp < 2; grp++) {
#pragma unroll
    for (int dt = 0; dt < 2; dt++) oacc[grp][dt] = (f32x4){0.f, 0.f, 0.f, 0.f};
    lacc[grp] = (f32x4){0.f, 0.f, 0.f, 0.f};
  }

  short onev = (l16 == 0) ? (short)0x3F80 : (short)0;
  bf16x8 aones = {onev, onev, onev, onev, onev, onev, onev, onev};

  for (int kc = kc0; kc < kc0 + 512; kc += 64) {
    bf16x8 F[4];
#pragma unroll
    for (int t = 0; t < 4; t++)
      F[t] = *(const bf16x8*)(fb + (size_t)(kc + t * 16 + l16) * 32 + quad * 8);
    bf16x8 H[2][2];
#pragma unroll
    for (int half = 0; half < 2; half++)
#pragma unroll
      for (int dt = 0; dt < 2; dt++)
        H[half][dt] = *(const bf16x8*)(hb + (size_t)(dt * 16 + l16) * 4096 +
                                       kc + half * 32 + quad * 8);

#pragma unroll
    for (int g = 0; g < 2; g++) {
      f32x4 s[4];
#pragma unroll
      for (int t = 0; t < 4; t++)
        s[t] = __builtin_amdgcn_mfma_f32_16x16x32_bf16(
            F[t], ga[g], (f32x4){0.f, 0.f, 0.f, 0.f}, 0, 0, 0);

      unsigned long long* prow64 = (unsigned long long*)&psh[wave][l16][0];
#pragma unroll
      for (int t = 0; t < 4; t++) {
        float p0 = EXP2(s[t][0]);
        float p1 = EXP2(s[t][1]);
        float p2 = EXP2(s[t][2]);
        float p3 = EXP2(s[t][3]);
        unsigned lo = __builtin_amdgcn_perm(__builtin_bit_cast(unsigned, p1),
                                            __builtin_bit_cast(unsigned, p0),
                                            0x07060302u);
        unsigned hi = __builtin_amdgcn_perm(__builtin_bit_cast(unsigned, p3),
                                            __builtin_bit_cast(unsigned, p2),
                                            0x07060302u);
        prow64[4 * t + quad] = ((unsigned long long)hi << 32) | lo;
      }
      asm volatile("" ::: "memory");

#pragma unroll
      for (int half = 0; half < 2; half++) {
        bf16x8 pa = *(const bf16x8*)(&psh[wave][l16][half * 32 + quad * 8]);
#pragma unroll
        for (int dt = 0; dt < 2; dt++)
          oacc[g][dt] = __builtin_amdgcn_mfma_f32_16x16x32_bf16(
              H[half][dt], pa, oacc[g][dt], 0, 0, 0);
        lacc[g] = __builtin_amdgcn_mfma_f32_16x16x32_bf16(aones, pa, lacc[g],
                                                          0, 0, 0);
      }
      asm volatile("" ::: "memory");
    }
  }

#pragma unroll
  for (int grp = 0; grp < 2; grp++) {
    size_t row = (size_t)b * 4096 + qbase + grp * 16 + l16;
    short* pod = po + ((size_t)z * 32768 + row) * 32;
#pragma unroll
    for (int dt = 0; dt < 2; dt++) {
      unsigned w0 = (unsigned)(unsigned short)f2bf(oacc[grp][dt][0]) |
                    ((unsigned)(unsigned short)f2bf(oacc[grp][dt][1]) << 16);
      unsigned w1 = (unsigned)(unsigned short)f2bf(oacc[grp][dt][2]) |
                    ((unsigned)(unsigned short)f2bf(oacc[grp][dt][3]) << 16);
      unsigned* dst = (unsigned*)(pod + dt * 16 + quad * 4);
      dst[0] = w0;
      dst[1] = w1;
    }
  }
  if (quad == 0) {
#pragma unroll
    for (int grp = 0; grp < 2; grp++)
      ls[(size_t)z * 32768 + (size_t)b * 4096 + qbase + grp * 16 + l16] =
          lacc[grp][0];
  }
}

// ---------------------------------------------------------------------------
// K3: sigma_v + Kvt LDS build + split-combine (x8) + output projection +
// residual. UNCHANGED round-4 version (control).
// ---------------------------------------------------------------------------
__global__ __launch_bounds__(256) void outproj_fused(
    const short* __restrict__ po, const float* __restrict__ ls,
    const float* __restrict__ wv, const float* __restrict__ uv,
    const float* __restrict__ bv, const float* __restrict__ gamma,
    const float* __restrict__ x, float* __restrict__ out) {
  __shared__ __align__(16) float osh[4][16][260];  // 66,560 B (proven size)
  short* kv = (short*)osh;                         // [256][40] = 20,480 B
  float* redp = (float*)((char*)osh + 20480);      // [256]
  float* svv = (float*)((char*)osh + 21504);       // [32]
  float* sclv = (float*)((char*)osh + 21632);      // [2]
  int tid = threadIdx.x;
  int wave = tid >> 6, lane = tid & 63;
  int quad = lane >> 4, l16 = lane & 15;

  // ---- sigma_v + Kvt build (redundant per block, deterministic) ----
  {
    int i = tid >> 3, p8 = tid & 7;
    float pv = 0.f;
#pragma unroll
    for (int k = 0; k < 32; k++) {
      int j = p8 * 32 + k;
      pv += uv[j] * wv[i * 256 + j];
    }
    redp[tid] = pv;
    __syncthreads();
    float vi = 0.f;
    if (tid < 32) {
#pragma unroll
      for (int p = 0; p < 8; p++) vi += redp[tid * 8 + p];
    }
    float q2 = (tid < 32) ? vi * vi : 0.f;
#pragma unroll
    for (int off = 32; off > 0; off >>= 1) q2 += __shfl_xor(q2, off);
    if (tid == 0) sclv[0] = sqrtf(fmaxf(q2, 1e-12f));
    __syncthreads();
    if (tid < 32) svv[tid] = vi / sclv[0];
    __syncthreads();
    float yc = 0.f;
#pragma unroll
    for (int i2 = 0; i2 < 32; i2++) yc += svv[i2] * wv[i2 * 256 + tid];
    float q3 = yc * yc;
#pragma unroll
    for (int off = 32; off > 0; off >>= 1) q3 += __shfl_xor(q3, off);
    if (lane == 0) redp[wave] = q3;
    __syncthreads();
    if (tid == 0) {
      float s2 = redp[0] + redp[1] + redp[2] + redp[3];
      float sig = s2 / sqrtf(fmaxf(s2, 1e-12f));
      sclv[1] = 1.0f / sig;
    }
    __syncthreads();
    float scv = sclv[1];
#pragma unroll
    for (int i2 = 0; i2 < 32; i2++)
      kv[tid * 40 + i2] = f2bf(wv[i2 * 256 + tid] * scv);
  }
  __syncthreads();

  // ---- split-combine + output projection (proven structure) ----
  int row0 = blockIdx.x * 64;
  int rbase = row0 + wave * 16;
  size_t row = (size_t)rbase + l16;

  float vacc[8];
#pragma unroll
  for (int j = 0; j < 8; j++) vacc[j] = 0.f;
  float l = 0.f;
#pragma unroll
  for (int z = 0; z < 8; z++) {
    const unsigned* p =
        (const unsigned*)(po + ((size_t)z * 32768 + row) * 32 + quad * 8);
#pragma unroll
    for (int j = 0; j < 4; j++) {
      unsigned w = p[j];
      vacc[2 * j] += __builtin_bit_cast(float, w << 16);
      vacc[2 * j + 1] += __builtin_bit_cast(float, w & 0xFFFF0000u);
    }
    l += ls[(size_t)z * 32768 + row];
  }
  float inv = 1.0f / l;
  bf16x8 va;
#pragma unroll
  for (int j = 0; j < 8; j++) va[j] = f2bf(vacc[j] * inv);

  float gm = gamma[0];

  f32x4 acc[16];
#pragma unroll
  for (int t = 0; t < 16; t++) {
    bf16x8 kf = *(const bf16x8*)&kv[(t * 16 + l16) * 40 + quad * 8];
    acc[t] = __builtin_amdgcn_mfma_f32_16x16x32_bf16(
        va, kf, (f32x4){0.f, 0.f, 0.f, 0.f}, 0, 0, 0);
  }
  __syncthreads();  // all kv reads done before osh overwrites the alias

#pragma unroll
  for (int t = 0; t < 16; t++) {
    float bb = bv[t * 16 + l16];
#pragma unroll
    for (int r = 0; r < 4; r++) {
      osh[wave][quad * 4 + r][t * 16 + l16] = acc[t][r] + bb;
    }
  }
  asm volatile("" ::: "memory");
  {
    int r_l = lane >> 2, c_l = lane & 3;
    int orow = row0 + wave * 16 + r_l;
    const float* oshr = &osh[wave][r_l][0];
    const float4* xr = (const float4*)(x + (size_t)orow * 256);
    float4* outr = (float4*)(out + (size_t)orow * 256);
#pragma unroll
    for (int i = 0; i < 16; i++) {
      int c4 = c_l + i * 4;
      float4 o4 = *(const float4*)&oshr[c4 * 4];
      float4 xv = xr[c4];
      float4 ov;
      ov.x = gm * o4.x + xv.x;
      ov.y = gm * o4.y + xv.y;
      ov.z = gm * o4.z + xv.z;
      ov.w = gm * o4.w + xv.w;
      outr[c4] = ov;
    }
  }
}

// ---------------------------------------------------------------------------
extern "C" void kernel_launch(void* const* d_in, const int* in_sizes, int n_in,
                              void* d_out, int out_size, void* d_ws,
                              size_t ws_size, hipStream_t stream) {
  const float* x = (const float*)d_in[0];
  const float* wf = (const float*)d_in[1];
  const float* bf = (const float*)d_in[2];
  const float* uf = (const float*)d_in[3];
  const float* wg = (const float*)d_in[4];
  const float* bg = (const float*)d_in[5];
  const float* ug = (const float*)d_in[6];
  const float* wh = (const float*)d_in[7];
  const float* bh = (const float*)d_in[8];
  const float* uh = (const float*)d_in[9];
  const float* wv = (const float*)d_in[10];
  const float* bv = (const float*)d_in[11];
  const float* uv = (const float*)d_in[12];
  const float* gamma = (const float*)d_in[13];
  float* out = (float*)d_out;

  char* ws = (char*)d_ws;
  short* fo = (short*)(ws + 2u * 1024 * 1024);   // 2 MB
  short* go = (short*)(ws + 4u * 1024 * 1024);   // 2 MB
  short* hto = (short*)(ws + 6u * 1024 * 1024);  // 2 MB (d-major)
  short* po = (short*)(ws + 10u * 1024 * 1024);  // 8*32768*32*2 = 16 MB
  float* lsp = (float*)(ws + 26u * 1024 * 1024); // 8*32768*4 = 1 MB

  proj_fused<<<512, 256, 0, stream>>>(x, wf, bf, uf, wg, bg, ug, wh, bh, uh,
                                      fo, go, hto);
  attn_kernel<<<dim3(32, 8, 8), 256, 0, stream>>>(go, fo, hto, po, lsp);
  outproj_fused<<<512, 256, 0, stream>>>(po, lsp, wv, uv, bv, gamma, x, out);
}

// Round 9
// 185.607 us; speedup vs baseline: 1.4760x; 1.4760x over previous
//
#include <hip/hip_runtime.h>
#include <math.h>

typedef __attribute__((ext_vector_type(8))) short bf16x8;
typedef __attribute__((ext_vector_type(4))) short bf16x4;
typedef __attribute__((ext_vector_type(4))) float f32x4;

#define LOG2E 1.4426950408889634f

#if __has_builtin(__builtin_amdgcn_exp2f)
#define EXP2(x) __builtin_amdgcn_exp2f(x)
#else
#define EXP2(x) exp2f(x)
#endif

static __device__ __forceinline__ short f2bf(float f) {
  unsigned u = __builtin_bit_cast(unsigned, f);
  u = u + 0x7FFFu + ((u >> 16) & 1u);   // RNE
  return (short)(u >> 16);
}

// ---------------------------------------------------------------------------
// K0: weight prep with fused sigma — ROUND-0 PROVEN KERNEL, verbatim.
// 128 blocks; blocks 0..95 build Wt column c=blk (f/g/h), 96..127 build Kvt.
// g pre-scaled by log2e. Runs once (~3 us); proj/outproj then read Wt/Kvt
// from global (64 KB, broadcast, L2-resident) with NO per-block sigma.
// ---------------------------------------------------------------------------
__global__ __launch_bounds__(256) void prep_weights(
    const float* __restrict__ wf, const float* __restrict__ wg,
    const float* __restrict__ wh, const float* __restrict__ wv,
    const float* __restrict__ uf, const float* __restrict__ ug,
    const float* __restrict__ uh, const float* __restrict__ uv,
    short* __restrict__ Wt, short* __restrict__ Kvt) {
  __shared__ float sv[256];
  __shared__ float red[256];
  int blk = blockIdx.x;
  int tid = threadIdx.x;
  int sel = (blk < 96) ? (blk >> 5) : 3;
  const float* w = (sel == 0) ? wf : (sel == 1) ? wg : (sel == 2) ? wh : wv;
  const float* u = (sel == 0) ? uf : (sel == 1) ? ug : (sel == 2) ? uh : uv;
  int IN = (sel < 3) ? 256 : 32;
  int OUT = (sel < 3) ? 32 : 256;

  float t = 0.f;
  if (tid < IN) {
    for (int j = 0; j < OUT; j++) t += u[j] * w[tid * OUT + j];
  }
  red[tid] = t * t;
  __syncthreads();
  for (int st = 128; st > 0; st >>= 1) {
    if (tid < st) red[tid] += red[tid + st];
    __syncthreads();
  }
  float nv = sqrtf(fmaxf(red[0], 1e-12f));
  sv[tid] = (tid < IN) ? t / nv : 0.f;
  __syncthreads();

  float s2 = 0.f;
  if (tid < OUT) {
    float sum = 0.f;
    for (int i = 0; i < IN; i++) sum += sv[i] * w[i * OUT + tid];
    s2 = sum * sum;
  }
  red[tid] = s2;
  __syncthreads();
  for (int st = 128; st > 0; st >>= 1) {
    if (tid < st) red[tid] += red[tid + st];
    __syncthreads();
  }
  float sum2 = red[0];
  float sigma = sum2 / sqrtf(fmaxf(sum2, 1e-12f));
  float scale = 1.0f / sigma;
  if (sel == 1) scale *= LOG2E;

  int idx = blk * 256 + tid;
  if (blk < 96) {
    int c = blk, k = tid;
    int cc = c & 31;
    Wt[idx] = f2bf(w[k * 32 + cc] * scale);
  } else {
    int i2 = idx - 96 * 256;
    int c = i2 >> 5, k = i2 & 31;
    Kvt[i2] = f2bf(wv[k * 256 + c] * scale);
  }
}

// ---------------------------------------------------------------------------
// K1: QKV projection, sigma-free. Round-4's register-afv prefetch (proven
// -24 us) kept; Wt read straight from global inside the MFMA loop (round-0
// pattern: 64 KB broadcast, L1/L2-resident). LDS drops 50 KB -> 8.4 KB
// (hsh only) and the 12-barrier sigma prologue disappears from all 512
// blocks.
// ---------------------------------------------------------------------------
__global__ __launch_bounds__(256) void proj_kernel(
    const float* __restrict__ x, const short* __restrict__ Wt,
    const float* __restrict__ bf_, const float* __restrict__ bg_,
    const float* __restrict__ bh_, short* __restrict__ fo,
    short* __restrict__ go, short* __restrict__ hto) {
  __shared__ float hsh[64][33];
  int tid = threadIdx.x;
  int wave = tid >> 6, lane = tid & 63;
  int quad = lane >> 4, l16 = lane & 15;
  int row0 = blockIdx.x * 64;

  // ---- prefetch x A-fragments (one row per lane, 8 k-chunks) ----
  const float* xr = x + (size_t)(row0 + wave * 16 + l16) * 256 + quad * 8;
  bf16x8 afv[8];
#pragma unroll
  for (int k8 = 0; k8 < 8; k8++) {
    float4 a0 = *(const float4*)(xr + k8 * 32);
    float4 a1 = *(const float4*)(xr + k8 * 32 + 4);
    bf16x8 a;
    a[0] = f2bf(a0.x); a[1] = f2bf(a0.y); a[2] = f2bf(a0.z); a[3] = f2bf(a0.w);
    a[4] = f2bf(a1.x); a[5] = f2bf(a1.y); a[6] = f2bf(a1.z); a[7] = f2bf(a1.w);
    afv[k8] = a;
  }

  // ---- MFMA main loop: B-fragments straight from global Wt ----
  f32x4 acc[6];
#pragma unroll
  for (int t = 0; t < 6; t++) acc[t] = (f32x4){0.f, 0.f, 0.f, 0.f};
#pragma unroll
  for (int k8 = 0; k8 < 8; k8++) {
    int kc = k8 * 32;
#pragma unroll
    for (int t = 0; t < 6; t++) {
      bf16x8 bfr = *(const bf16x8*)(Wt + (t * 16 + l16) * 256 + kc + quad * 8);
      acc[t] =
          __builtin_amdgcn_mfma_f32_16x16x32_bf16(afv[k8], bfr, acc[t], 0, 0, 0);
    }
  }

  // ---- epilogue: f/g stores, h transpose via LDS ----
  int b = row0 >> 12;
  int n0 = row0 & 4095;
  int rbase = row0 + wave * 16;
#pragma unroll
  for (int t = 0; t < 4; t++) {
    int c = t * 16 + l16;
    int se = c >> 5, cc = c & 31;
    float bb = se ? (bg_[cc] * LOG2E) : bf_[cc];
    short* dst = se ? go : fo;
#pragma unroll
    for (int r = 0; r < 4; r++) {
      int row = rbase + quad * 4 + r;
      dst[(size_t)row * 32 + cc] = f2bf(acc[t][r] + bb);
    }
  }
#pragma unroll
  for (int t = 4; t < 6; t++) {
    int cc = (t - 4) * 16 + l16;
    float bb = bh_[cc];
#pragma unroll
    for (int r = 0; r < 4; r++)
      hsh[wave * 16 + quad * 4 + r][cc] = acc[t][r] + bb;
  }
  __syncthreads();
  {
    int d = tid >> 3, ng = tid & 7;
    bf16x8 tmp;
#pragma unroll
    for (int i = 0; i < 8; i++) tmp[i] = f2bf(hsh[ng * 8 + i][d]);
    *(bf16x8*)(hto + (size_t)(b * 32 + d) * 4096 + n0 + ng * 8) = tmp;
  }
}

// ---------------------------------------------------------------------------
// K2: flash attention — ROUND-6 EXACT KERNEL (165.0-proven). XCD remap
// (FETCH 18.5->10.8 MB) + 4 blocks/CU blocking. Round-3/8 lesson is now
// two-sided: 8 blocks/CU thrashes per-XCD L2 (FETCH ~172-196 MB, WRITE
// ~360-418 MB) WITH OR WITHOUT the remap — the in-flight read+write
// footprint of 8 blocks/CU exceeds 4 MiB regardless of combo pinning.
// Do not raise occupancy.
// ---------------------------------------------------------------------------
__global__ __launch_bounds__(256, 4) void attn_kernel(
    const short* __restrict__ g_, const short* __restrict__ f_,
    const short* __restrict__ ht_, short* __restrict__ po,
    float* __restrict__ ls) {
  __shared__ __align__(16) short psh[4][4][16][72];
  int lin = blockIdx.x + (blockIdx.y << 4) + (blockIdx.z << 7);
  int xcd = lin & 7;
  int s8 = lin >> 3;                 // sequence index within XCD (0..127)
  int combo = xcd * 8 + (s8 >> 4);   // (b,z) combo 0..63, 8 per XCD
  int qt = s8 & 15;                  // q-tile 0..15
  int z = combo >> 3;
  int b = combo & 7;
  int wave = threadIdx.x >> 6;
  int lane = threadIdx.x & 63;
  int quad = lane >> 4, l16 = lane & 15;
  int qbase = qt * 256 + wave * 64;
  int kc0 = z * 512;

  const short* fb = f_ + (size_t)b * 4096 * 32;
  const short* hb = ht_ + (size_t)b * 32 * 4096;

  bf16x8 ga[4];
#pragma unroll
  for (int grp = 0; grp < 4; grp++)
    ga[grp] = *(const bf16x8*)(g_ + (size_t)(b * 4096 + qbase + grp * 16 + l16) * 32 +
                               quad * 8);

  f32x4 oacc[4][2];
  f32x4 lacc[4];
#pragma unroll
  for (int grp = 0; grp < 4; grp++) {
#pragma unroll
    for (int dt = 0; dt < 2; dt++) oacc[grp][dt] = (f32x4){0.f, 0.f, 0.f, 0.f};
    lacc[grp] = (f32x4){0.f, 0.f, 0.f, 0.f};
  }

  short onev = (l16 == 0) ? (short)0x3F80 : (short)0;
  bf16x8 aones = {onev, onev, onev, onev, onev, onev, onev, onev};

  for (int kc = kc0; kc < kc0 + 512; kc += 64) {
    bf16x8 F[4];
#pragma unroll
    for (int t = 0; t < 4; t++)
      F[t] = *(const bf16x8*)(fb + (size_t)(kc + t * 16 + l16) * 32 + quad * 8);
    bf16x8 H[2][2];
#pragma unroll
    for (int half = 0; half < 2; half++)
#pragma unroll
      for (int dt = 0; dt < 2; dt++)
        H[half][dt] = *(const bf16x8*)(hb + (size_t)(dt * 16 + l16) * 4096 +
                                       kc + half * 32 + quad * 8);

#pragma unroll
    for (int g = 0; g < 4; g++) {
      f32x4 s[4];
#pragma unroll
      for (int t = 0; t < 4; t++)
        s[t] = __builtin_amdgcn_mfma_f32_16x16x32_bf16(
            F[t], ga[g], (f32x4){0.f, 0.f, 0.f, 0.f}, 0, 0, 0);

      unsigned long long* prow64 = (unsigned long long*)&psh[wave][g][l16][0];
#pragma unroll
      for (int t = 0; t < 4; t++) {
        float p0 = EXP2(s[t][0]);
        float p1 = EXP2(s[t][1]);
        float p2 = EXP2(s[t][2]);
        float p3 = EXP2(s[t][3]);
        unsigned lo = __builtin_amdgcn_perm(__builtin_bit_cast(unsigned, p1),
                                            __builtin_bit_cast(unsigned, p0),
                                            0x07060302u);
        unsigned hi = __builtin_amdgcn_perm(__builtin_bit_cast(unsigned, p3),
                                            __builtin_bit_cast(unsigned, p2),
                                            0x07060302u);
        prow64[4 * t + quad] = ((unsigned long long)hi << 32) | lo;
      }
      asm volatile("" ::: "memory");

#pragma unroll
      for (int half = 0; half < 2; half++) {
        bf16x8 pa = *(const bf16x8*)(&psh[wave][g][l16][half * 32 + quad * 8]);
#pragma unroll
        for (int dt = 0; dt < 2; dt++)
          oacc[g][dt] = __builtin_amdgcn_mfma_f32_16x16x32_bf16(
              H[half][dt], pa, oacc[g][dt], 0, 0, 0);
        lacc[g] = __builtin_amdgcn_mfma_f32_16x16x32_bf16(aones, pa, lacc[g],
                                                          0, 0, 0);
      }
      asm volatile("" ::: "memory");
    }
  }

#pragma unroll
  for (int grp = 0; grp < 4; grp++) {
    size_t row = (size_t)b * 4096 + qbase + grp * 16 + l16;
    short* pod = po + ((size_t)z * 32768 + row) * 32;
#pragma unroll
    for (int dt = 0; dt < 2; dt++) {
      unsigned w0 = (unsigned)(unsigned short)f2bf(oacc[grp][dt][0]) |
                    ((unsigned)(unsigned short)f2bf(oacc[grp][dt][1]) << 16);
      unsigned w1 = (unsigned)(unsigned short)f2bf(oacc[grp][dt][2]) |
                    ((unsigned)(unsigned short)f2bf(oacc[grp][dt][3]) << 16);
      unsigned* dst = (unsigned*)(pod + dt * 16 + quad * 4);
      dst[0] = w0;
      dst[1] = w1;
    }
  }
  if (quad == 0) {
#pragma unroll
    for (int grp = 0; grp < 4; grp++)
      ls[(size_t)z * 32768 + (size_t)b * 4096 + qbase + grp * 16 + l16] =
          lacc[grp][0];
  }
}

// ---------------------------------------------------------------------------
// K3: split-combine (x8) + output projection + residual, sigma-free.
// Round-4 proven combine/MFMA/epilogue; Kvt read from global (round-0
// pattern, 16 KB broadcast). The 8-barrier sigma_v prologue disappears
// from all 512 blocks.
// ---------------------------------------------------------------------------
__global__ __launch_bounds__(256) void outproj_kernel(
    const short* __restrict__ po, const float* __restrict__ ls,
    const short* __restrict__ Kvt, const float* __restrict__ bv,
    const float* __restrict__ gamma, const float* __restrict__ x,
    float* __restrict__ out) {
  __shared__ __align__(16) float osh[4][16][260];  // proven epilogue size
  int tid = threadIdx.x;
  int wave = tid >> 6, lane = tid & 63;
  int quad = lane >> 4, l16 = lane & 15;

  int row0 = blockIdx.x * 64;
  int rbase = row0 + wave * 16;
  size_t row = (size_t)rbase + l16;

  float vacc[8];
#pragma unroll
  for (int j = 0; j < 8; j++) vacc[j] = 0.f;
  float l = 0.f;
#pragma unroll
  for (int z = 0; z < 8; z++) {
    const unsigned* p =
        (const unsigned*)(po + ((size_t)z * 32768 + row) * 32 + quad * 8);
#pragma unroll
    for (int j = 0; j < 4; j++) {
      unsigned w = p[j];
      vacc[2 * j] += __builtin_bit_cast(float, w << 16);
      vacc[2 * j + 1] += __builtin_bit_cast(float, w & 0xFFFF0000u);
    }
    l += ls[(size_t)z * 32768 + row];
  }
  float inv = 1.0f / l;
  bf16x8 va;
#pragma unroll
  for (int j = 0; j < 8; j++) va[j] = f2bf(vacc[j] * inv);

  float gm = gamma[0];

  f32x4 acc[16];
#pragma unroll
  for (int t = 0; t < 16; t++) {
    bf16x8 kf = *(const bf16x8*)(Kvt + (t * 16 + l16) * 32 + quad * 8);
    acc[t] = __builtin_amdgcn_mfma_f32_16x16x32_bf16(
        va, kf, (f32x4){0.f, 0.f, 0.f, 0.f}, 0, 0, 0);
  }

#pragma unroll
  for (int t = 0; t < 16; t++) {
    float bb = bv[t * 16 + l16];
#pragma unroll
    for (int r = 0; r < 4; r++) {
      osh[wave][quad * 4 + r][t * 16 + l16] = acc[t][r] + bb;
    }
  }
  asm volatile("" ::: "memory");
  {
    int r_l = lane >> 2, c_l = lane & 3;
    int orow = row0 + wave * 16 + r_l;
    const float* oshr = &osh[wave][r_l][0];
    const float4* xr = (const float4*)(x + (size_t)orow * 256);
    float4* outr = (float4*)(out + (size_t)orow * 256);
#pragma unroll
    for (int i = 0; i < 16; i++) {
      int c4 = c_l + i * 4;
      float4 o4 = *(const float4*)&oshr[c4 * 4];
      float4 xv = xr[c4];
      float4 ov;
      ov.x = gm * o4.x + xv.x;
      ov.y = gm * o4.y + xv.y;
      ov.z = gm * o4.z + xv.z;
      ov.w = gm * o4.w + xv.w;
      outr[c4] = ov;
    }
  }
}

// ---------------------------------------------------------------------------
extern "C" void kernel_launch(void* const* d_in, const int* in_sizes, int n_in,
                              void* d_out, int out_size, void* d_ws,
                              size_t ws_size, hipStream_t stream) {
  const float* x = (const float*)d_in[0];
  const float* wf = (const float*)d_in[1];
  const float* bf = (const float*)d_in[2];
  const float* uf = (const float*)d_in[3];
  const float* wg = (const float*)d_in[4];
  const float* bg = (const float*)d_in[5];
  const float* ug = (const float*)d_in[6];
  const float* wh = (const float*)d_in[7];
  const float* bh = (const float*)d_in[8];
  const float* uh = (const float*)d_in[9];
  const float* wv = (const float*)d_in[10];
  const float* bv = (const float*)d_in[11];
  const float* uv = (const float*)d_in[12];
  const float* gamma = (const float*)d_in[13];
  float* out = (float*)d_out;

  char* ws = (char*)d_ws;
  short* Wt = (short*)(ws + 1024);                   // 48 KB
  short* Kvt = (short*)(ws + 64 * 1024);             // 16 KB
  short* fo = (short*)(ws + 2u * 1024 * 1024);       // 2 MB
  short* go = (short*)(ws + 4u * 1024 * 1024);       // 2 MB
  short* hto = (short*)(ws + 6u * 1024 * 1024);      // 2 MB (d-major)
  short* po = (short*)(ws + 10u * 1024 * 1024);      // 16 MB
  float* lsp = (float*)(ws + 26u * 1024 * 1024);     // 1 MB

  prep_weights<<<128, 256, 0, stream>>>(wf, wg, wh, wv, uf, ug, uh, uv, Wt, Kvt);
  proj_kernel<<<512, 256, 0, stream>>>(x, Wt, bf, bg, bh, fo, go, hto);
  attn_kernel<<<dim3(16, 8, 8), 256, 0, stream>>>(go, fo, hto, po, lsp);
  outproj_kernel<<<512, 256, 0, stream>>>(po, lsp, Kvt, bv, gamma, x, out);
}

// Round 10
// 163.577 us; speedup vs baseline: 1.6747x; 1.1347x over previous
//
#include <hip/hip_runtime.h>
#include <math.h>

typedef __attribute__((ext_vector_type(8))) short bf16x8;
typedef __attribute__((ext_vector_type(4))) short bf16x4;
typedef __attribute__((ext_vector_type(4))) float f32x4;

#define LOG2E 1.4426950408889634f

#if __has_builtin(__builtin_amdgcn_exp2f)
#define EXP2(x) __builtin_amdgcn_exp2f(x)
#else
#define EXP2(x) exp2f(x)
#endif

static __device__ __forceinline__ short f2bf(float f) {
  unsigned u = __builtin_bit_cast(unsigned, f);
  u = u + 0x7FFFu + ((u >> 16) & 1u);   // RNE
  return (short)(u >> 16);
}

// ---------------------------------------------------------------------------
// K1: fused sigma + QKV projection (round-6 exact; best-measured config).
// x A-frags prefetched FIRST so the sigma chain executes under the in-flight
// HBM reads (round-9 lesson: un-fusing re-exposes this latency, +20 us).
// Per-sel register w-row reuse proven in round 4 (-24 us).
// ---------------------------------------------------------------------------
__global__ __launch_bounds__(256) void proj_fused(
    const float* __restrict__ x,
    const float* __restrict__ wf, const float* __restrict__ bf_,
    const float* __restrict__ uf,
    const float* __restrict__ wg, const float* __restrict__ bg_,
    const float* __restrict__ ug,
    const float* __restrict__ wh, const float* __restrict__ bh_,
    const float* __restrict__ uh,
    short* __restrict__ fo, short* __restrict__ go, short* __restrict__ hto) {
  __shared__ __align__(16) short wt[96 * 256];  // 48 KB (hsh aliases later)
  __shared__ float red[256];
  __shared__ float svx[256];
  __shared__ float scl[3];
  int tid = threadIdx.x;
  int wave = tid >> 6, lane = tid & 63;
  int quad = lane >> 4, l16 = lane & 15;
  int row0 = blockIdx.x * 64;

  // ---- prefetch x A-fragments (one row per lane, 8 k-chunks) ----
  const float* xr = x + (size_t)(row0 + wave * 16 + l16) * 256 + quad * 8;
  bf16x8 afv[8];
#pragma unroll
  for (int k8 = 0; k8 < 8; k8++) {
    float4 a0 = *(const float4*)(xr + k8 * 32);
    float4 a1 = *(const float4*)(xr + k8 * 32 + 4);
    bf16x8 a;
    a[0] = f2bf(a0.x); a[1] = f2bf(a0.y); a[2] = f2bf(a0.z); a[3] = f2bf(a0.w);
    a[4] = f2bf(a1.x); a[5] = f2bf(a1.y); a[6] = f2bf(a1.z); a[7] = f2bf(a1.w);
    afv[k8] = a;
  }

  // ---- per-sel: sigma + Wt build from the SAME register copy of w ----
#pragma unroll 1
  for (int sel = 0; sel < 3; sel++) {
    const float* w = (sel == 0) ? wf : (sel == 1) ? wg : wh;
    const float* u = (sel == 0) ? uf : (sel == 1) ? ug : uh;

    float wr[32];
    {
      const float4* wrow = (const float4*)(w + tid * 32);
#pragma unroll
      for (int q4 = 0; q4 < 8; q4++) {
        float4 v = wrow[q4];
        wr[4 * q4 + 0] = v.x; wr[4 * q4 + 1] = v.y;
        wr[4 * q4 + 2] = v.z; wr[4 * q4 + 3] = v.w;
      }
    }
    // stage 1: t = u . w[tid][:]
    float t = 0.f;
#pragma unroll
    for (int j = 0; j < 32; j++) t += u[j] * wr[j];
    float v2 = t * t;
#pragma unroll
    for (int off = 32; off > 0; off >>= 1) v2 += __shfl_xor(v2, off);
    if (lane == 0) red[wave] = v2;
    __syncthreads();
    float nv = sqrtf(fmaxf(red[0] + red[1] + red[2] + red[3], 1e-12f));
    svx[tid] = t / nv;
    __syncthreads();
    // stage 2: y[c] = sum_i sv[i] * w[i][c]  (coalesced, L1/L2-hot)
    int c = tid & 31, part = tid >> 5;
    float p = 0.f;
#pragma unroll
    for (int k = 0; k < 32; k++) {
      int i = part * 32 + k;
      p += svx[i] * w[i * 32 + c];
    }
    red[tid] = p;
    __syncthreads();
    float q2 = 0.f;
    if (tid < 32) {
      float s_c = 0.f;
#pragma unroll
      for (int pp = 0; pp < 8; pp++) s_c += red[tid + 32 * pp];
      q2 = s_c * s_c;
    }
#pragma unroll
    for (int off = 32; off > 0; off >>= 1) q2 += __shfl_xor(q2, off);
    if (tid == 0) {
      float s2 = q2;
      float sig = s2 / sqrtf(fmaxf(s2, 1e-12f));
      float s = 1.0f / sig;
      if (sel == 1) s *= LOG2E;
      scl[sel] = s;
    }
    __syncthreads();
    // build Wt rows sel*32..+31 straight from registers (swizzle unchanged)
    float s = scl[sel];
#pragma unroll
    for (int cc = 0; cc < 32; cc++) {
      wt[(sel * 32 + cc) * 256 + (tid ^ ((cc & 15) << 3))] = f2bf(wr[cc] * s);
    }
    __syncthreads();  // red/svx reused next sel; last iter guards MFMA reads
  }

  // ---- MFMA main loop ----
  f32x4 acc[6];
#pragma unroll
  for (int t = 0; t < 6; t++) acc[t] = (f32x4){0.f, 0.f, 0.f, 0.f};
#pragma unroll
  for (int k8 = 0; k8 < 8; k8++) {
    int kc = k8 * 32;
#pragma unroll
    for (int t = 0; t < 6; t++) {
      int rw = t * 16 + l16;
      bf16x8 bfr =
          *(const bf16x8*)&wt[rw * 256 + ((kc + quad * 8) ^ (l16 << 3))];
      acc[t] =
          __builtin_amdgcn_mfma_f32_16x16x32_bf16(afv[k8], bfr, acc[t], 0, 0, 0);
    }
  }
  __syncthreads();  // all wt reads done before hsh aliases it

  // ---- epilogue: f/g stores, h transpose via LDS ----
  float* hsh = (float*)wt;  // [64][33]
  int b = row0 >> 12;
  int n0 = row0 & 4095;
  int rbase = row0 + wave * 16;
#pragma unroll
  for (int t = 0; t < 4; t++) {
    int c = t * 16 + l16;
    int se = c >> 5, cc = c & 31;
    float bb = se ? (bg_[cc] * LOG2E) : bf_[cc];
    short* dst = se ? go : fo;
#pragma unroll
    for (int r = 0; r < 4; r++) {
      int row = rbase + quad * 4 + r;
      dst[(size_t)row * 32 + cc] = f2bf(acc[t][r] + bb);
    }
  }
#pragma unroll
  for (int t = 4; t < 6; t++) {
    int cc = (t - 4) * 16 + l16;
    float bb = bh_[cc];
#pragma unroll
    for (int r = 0; r < 4; r++)
      hsh[(wave * 16 + quad * 4 + r) * 33 + cc] = acc[t][r] + bb;
  }
  __syncthreads();
  {
    int d = tid >> 3, ng = tid & 7;
    bf16x8 tmp;
#pragma unroll
    for (int i = 0; i < 8; i++) tmp[i] = f2bf(hsh[(ng * 8 + i) * 33 + d]);
    *(bf16x8*)(hto + (size_t)(b * 32 + d) * 4096 + n0 + ng * 8) = tmp;
  }
}

// ---------------------------------------------------------------------------
// K2: flash attention (round-6 exact). XCD remap: each XCD owns 8 (b,z)
// combos (FETCH 18.5->10.8 MB, proven). 4 blocks/CU blocking is load-bearing
// (rounds 3+8, two-sided proof): 8 blocks/CU thrashes per-XCD L2 with or
// without the remap (FETCH ~172-196 MB, WRITE ~360-418 MB, attn 44->146 us).
// sw-pipelining the g-loop also falsified (round 7, +2 us). Do not touch.
// ---------------------------------------------------------------------------
__global__ __launch_bounds__(256, 4) void attn_kernel(
    const short* __restrict__ g_, const short* __restrict__ f_,
    const short* __restrict__ ht_, short* __restrict__ po,
    float* __restrict__ ls) {
  __shared__ __align__(16) short psh[4][4][16][72];
  int lin = blockIdx.x + (blockIdx.y << 4) + (blockIdx.z << 7);
  int xcd = lin & 7;
  int s8 = lin >> 3;                 // sequence index within XCD (0..127)
  int combo = xcd * 8 + (s8 >> 4);   // (b,z) combo 0..63, 8 per XCD
  int qt = s8 & 15;                  // q-tile 0..15
  int z = combo >> 3;
  int b = combo & 7;
  int wave = threadIdx.x >> 6;
  int lane = threadIdx.x & 63;
  int quad = lane >> 4, l16 = lane & 15;
  int qbase = qt * 256 + wave * 64;
  int kc0 = z * 512;

  const short* fb = f_ + (size_t)b * 4096 * 32;
  const short* hb = ht_ + (size_t)b * 32 * 4096;

  bf16x8 ga[4];
#pragma unroll
  for (int grp = 0; grp < 4; grp++)
    ga[grp] = *(const bf16x8*)(g_ + (size_t)(b * 4096 + qbase + grp * 16 + l16) * 32 +
                               quad * 8);

  f32x4 oacc[4][2];
  f32x4 lacc[4];
#pragma unroll
  for (int grp = 0; grp < 4; grp++) {
#pragma unroll
    for (int dt = 0; dt < 2; dt++) oacc[grp][dt] = (f32x4){0.f, 0.f, 0.f, 0.f};
    lacc[grp] = (f32x4){0.f, 0.f, 0.f, 0.f};
  }

  short onev = (l16 == 0) ? (short)0x3F80 : (short)0;
  bf16x8 aones = {onev, onev, onev, onev, onev, onev, onev, onev};

  for (int kc = kc0; kc < kc0 + 512; kc += 64) {
    bf16x8 F[4];
#pragma unroll
    for (int t = 0; t < 4; t++)
      F[t] = *(const bf16x8*)(fb + (size_t)(kc + t * 16 + l16) * 32 + quad * 8);
    bf16x8 H[2][2];
#pragma unroll
    for (int half = 0; half < 2; half++)
#pragma unroll
      for (int dt = 0; dt < 2; dt++)
        H[half][dt] = *(const bf16x8*)(hb + (size_t)(dt * 16 + l16) * 4096 +
                                       kc + half * 32 + quad * 8);

#pragma unroll
    for (int g = 0; g < 4; g++) {
      f32x4 s[4];
#pragma unroll
      for (int t = 0; t < 4; t++)
        s[t] = __builtin_amdgcn_mfma_f32_16x16x32_bf16(
            F[t], ga[g], (f32x4){0.f, 0.f, 0.f, 0.f}, 0, 0, 0);

      unsigned long long* prow64 = (unsigned long long*)&psh[wave][g][l16][0];
#pragma unroll
      for (int t = 0; t < 4; t++) {
        float p0 = EXP2(s[t][0]);
        float p1 = EXP2(s[t][1]);
        float p2 = EXP2(s[t][2]);
        float p3 = EXP2(s[t][3]);
        unsigned lo = __builtin_amdgcn_perm(__builtin_bit_cast(unsigned, p1),
                                            __builtin_bit_cast(unsigned, p0),
                                            0x07060302u);
        unsigned hi = __builtin_amdgcn_perm(__builtin_bit_cast(unsigned, p3),
                                            __builtin_bit_cast(unsigned, p2),
                                            0x07060302u);
        prow64[4 * t + quad] = ((unsigned long long)hi << 32) | lo;
      }
      asm volatile("" ::: "memory");

#pragma unroll
      for (int half = 0; half < 2; half++) {
        bf16x8 pa = *(const bf16x8*)(&psh[wave][g][l16][half * 32 + quad * 8]);
#pragma unroll
        for (int dt = 0; dt < 2; dt++)
          oacc[g][dt] = __builtin_amdgcn_mfma_f32_16x16x32_bf16(
              H[half][dt], pa, oacc[g][dt], 0, 0, 0);
        lacc[g] = __builtin_amdgcn_mfma_f32_16x16x32_bf16(aones, pa, lacc[g],
                                                          0, 0, 0);
      }
      asm volatile("" ::: "memory");
    }
  }

#pragma unroll
  for (int grp = 0; grp < 4; grp++) {
    size_t row = (size_t)b * 4096 + qbase + grp * 16 + l16;
    short* pod = po + ((size_t)z * 32768 + row) * 32;
#pragma unroll
    for (int dt = 0; dt < 2; dt++) {
      unsigned w0 = (unsigned)(unsigned short)f2bf(oacc[grp][dt][0]) |
                    ((unsigned)(unsigned short)f2bf(oacc[grp][dt][1]) << 16);
      unsigned w1 = (unsigned)(unsigned short)f2bf(oacc[grp][dt][2]) |
                    ((unsigned)(unsigned short)f2bf(oacc[grp][dt][3]) << 16);
      unsigned* dst = (unsigned*)(pod + dt * 16 + quad * 4);
      dst[0] = w0;
      dst[1] = w1;
    }
  }
  if (quad == 0) {
#pragma unroll
    for (int grp = 0; grp < 4; grp++)
      ls[(size_t)z * 32768 + (size_t)b * 4096 + qbase + grp * 16 + l16] =
          lacc[grp][0];
  }
}

// ---------------------------------------------------------------------------
// K3: sigma_v + Kvt LDS build + split-combine (x8) + output projection +
// residual (round-6 exact = round-4 proven version). The fused sigma_v
// prologue rides under the po-load latency (round-9 lesson); the [16][260]
// epilogue + no min-waves clamp avoids round-5's VGPR-cap regression.
// ---------------------------------------------------------------------------
__global__ __launch_bounds__(256) void outproj_fused(
    const short* __restrict__ po, const float* __restrict__ ls,
    const float* __restrict__ wv, const float* __restrict__ uv,
    const float* __restrict__ bv, const float* __restrict__ gamma,
    const float* __restrict__ x, float* __restrict__ out) {
  __shared__ __align__(16) float osh[4][16][260];  // 66,560 B (proven size)
  short* kv = (short*)osh;                         // [256][40] = 20,480 B
  float* redp = (float*)((char*)osh + 20480);      // [256]
  float* svv = (float*)((char*)osh + 21504);       // [32]
  float* sclv = (float*)((char*)osh + 21632);      // [2]
  int tid = threadIdx.x;
  int wave = tid >> 6, lane = tid & 63;
  int quad = lane >> 4, l16 = lane & 15;

  // ---- sigma_v + Kvt build (redundant per block, deterministic) ----
  {
    int i = tid >> 3, p8 = tid & 7;
    float pv = 0.f;
#pragma unroll
    for (int k = 0; k < 32; k++) {
      int j = p8 * 32 + k;
      pv += uv[j] * wv[i * 256 + j];
    }
    redp[tid] = pv;
    __syncthreads();
    float vi = 0.f;
    if (tid < 32) {
#pragma unroll
      for (int p = 0; p < 8; p++) vi += redp[tid * 8 + p];
    }
    float q2 = (tid < 32) ? vi * vi : 0.f;
#pragma unroll
    for (int off = 32; off > 0; off >>= 1) q2 += __shfl_xor(q2, off);
    if (tid == 0) sclv[0] = sqrtf(fmaxf(q2, 1e-12f));
    __syncthreads();
    if (tid < 32) svv[tid] = vi / sclv[0];
    __syncthreads();
    float yc = 0.f;
#pragma unroll
    for (int i2 = 0; i2 < 32; i2++) yc += svv[i2] * wv[i2 * 256 + tid];
    float q3 = yc * yc;
#pragma unroll
    for (int off = 32; off > 0; off >>= 1) q3 += __shfl_xor(q3, off);
    if (lane == 0) redp[wave] = q3;
    __syncthreads();
    if (tid == 0) {
      float s2 = redp[0] + redp[1] + redp[2] + redp[3];
      float sig = s2 / sqrtf(fmaxf(s2, 1e-12f));
      sclv[1] = 1.0f / sig;
    }
    __syncthreads();
    float scv = sclv[1];
#pragma unroll
    for (int i2 = 0; i2 < 32; i2++)
      kv[tid * 40 + i2] = f2bf(wv[i2 * 256 + tid] * scv);
  }
  __syncthreads();

  // ---- split-combine + output projection (proven structure) ----
  int row0 = blockIdx.x * 64;
  int rbase = row0 + wave * 16;
  size_t row = (size_t)rbase + l16;

  float vacc[8];
#pragma unroll
  for (int j = 0; j < 8; j++) vacc[j] = 0.f;
  float l = 0.f;
#pragma unroll
  for (int z = 0; z < 8; z++) {
    const unsigned* p =
        (const unsigned*)(po + ((size_t)z * 32768 + row) * 32 + quad * 8);
#pragma unroll
    for (int j = 0; j < 4; j++) {
      unsigned w = p[j];
      vacc[2 * j] += __builtin_bit_cast(float, w << 16);
      vacc[2 * j + 1] += __builtin_bit_cast(float, w & 0xFFFF0000u);
    }
    l += ls[(size_t)z * 32768 + row];
  }
  float inv = 1.0f / l;
  bf16x8 va;
#pragma unroll
  for (int j = 0; j < 8; j++) va[j] = f2bf(vacc[j] * inv);

  float gm = gamma[0];

  f32x4 acc[16];
#pragma unroll
  for (int t = 0; t < 16; t++) {
    bf16x8 kf = *(const bf16x8*)&kv[(t * 16 + l16) * 40 + quad * 8];
    acc[t] = __builtin_amdgcn_mfma_f32_16x16x32_bf16(
        va, kf, (f32x4){0.f, 0.f, 0.f, 0.f}, 0, 0, 0);
  }
  __syncthreads();  // all kv reads done before osh overwrites the alias

#pragma unroll
  for (int t = 0; t < 16; t++) {
    float bb = bv[t * 16 + l16];
#pragma unroll
    for (int r = 0; r < 4; r++) {
      osh[wave][quad * 4 + r][t * 16 + l16] = acc[t][r] + bb;
    }
  }
  asm volatile("" ::: "memory");
  {
    int r_l = lane >> 2, c_l = lane & 3;
    int orow = row0 + wave * 16 + r_l;
    const float* oshr = &osh[wave][r_l][0];
    const float4* xr = (const float4*)(x + (size_t)orow * 256);
    float4* outr = (float4*)(out + (size_t)orow * 256);
#pragma unroll
    for (int i = 0; i < 16; i++) {
      int c4 = c_l + i * 4;
      float4 o4 = *(const float4*)&oshr[c4 * 4];
      float4 xv = xr[c4];
      float4 ov;
      ov.x = gm * o4.x + xv.x;
      ov.y = gm * o4.y + xv.y;
      ov.z = gm * o4.z + xv.z;
      ov.w = gm * o4.w + xv.w;
      outr[c4] = ov;
    }
  }
}

// ---------------------------------------------------------------------------
extern "C" void kernel_launch(void* const* d_in, const int* in_sizes, int n_in,
                              void* d_out, int out_size, void* d_ws,
                              size_t ws_size, hipStream_t stream) {
  const float* x = (const float*)d_in[0];
  const float* wf = (const float*)d_in[1];
  const float* bf = (const float*)d_in[2];
  const float* uf = (const float*)d_in[3];
  const float* wg = (const float*)d_in[4];
  const float* bg = (const float*)d_in[5];
  const float* ug = (const float*)d_in[6];
  const float* wh = (const float*)d_in[7];
  const float* bh = (const float*)d_in[8];
  const float* uh = (const float*)d_in[9];
  const float* wv = (const float*)d_in[10];
  const float* bv = (const float*)d_in[11];
  const float* uv = (const float*)d_in[12];
  const float* gamma = (const float*)d_in[13];
  float* out = (float*)d_out;

  char* ws = (char*)d_ws;
  short* fo = (short*)(ws + 2u * 1024 * 1024);   // 2 MB
  short* go = (short*)(ws + 4u * 1024 * 1024);   // 2 MB
  short* hto = (short*)(ws + 6u * 1024 * 1024);  // 2 MB (d-major)
  short* po = (short*)(ws + 10u * 1024 * 1024);  // 8*32768*32*2 = 16 MB
  float* lsp = (float*)(ws + 26u * 1024 * 1024); // 8*32768*4 = 1 MB

  proj_fused<<<512, 256, 0, stream>>>(x, wf, bf, uf, wg, bg, ug, wh, bh, uh,
                                      fo, go, hto);
  attn_kernel<<<dim3(16, 8, 8), 256, 0, stream>>>(go, fo, hto, po, lsp);
  outproj_fused<<<512, 256, 0, stream>>>(po, lsp, wv, uv, bv, gamma, x, out);
}